// Round 23
// baseline (121.262 us; speedup 1.0000x reference)
//
#include <hip/hip_runtime.h>
#include <math.h>

#define BB 2
#define CIN 3
#define IMGD 128
#define HID 64
#define HEADS 4
#define DIM 16
#define PP 64
#define SS 4096
#define NCLS 2
#define EPSV 1e-5f
#define NQ 32768

// ws layout in floats
#define OQ_OFF   0         // [4][NQ][16] = 2,097,152 (AoS, coalesced float4 stores)
#define P_OFF    0         // pooled conv pre-BN (overlays oq; dead before attn)
#define LQ_OFF   2097152   // [4][NQ] = 131,072
#define KBF_OFF  2228224   // bf16 K [8][4096][16]; red2[128][16] overlays after k_attn
#define VTB_OFF  2490368   // bf16 V^T [8][16][4096] (pair-permuted) -> 262,144 f32 slots
#define STAT_OFF 2752512   // 128
#define ACC_OFF  2752640   // 128 (unused now)
#define Q_OFF    2752768   // q f32 (b,h,s,d) 524,288
#define RWT_OFF  3277056   // bf16 rw table [8][4096][64]; pstat[512][128] overlays BEFORE k_rwt

typedef short bf16x8 __attribute__((ext_vector_type(8)));
typedef float f32x4 __attribute__((ext_vector_type(4)));

__device__ __forceinline__ unsigned short f2bf(float f) {
    unsigned int u = __float_as_uint(f);
    u += 0x7FFFu + ((u >> 16) & 1u);
    return (unsigned short)(u >> 16);
}
__device__ __forceinline__ unsigned int pk2(float lo, float hi) {
    return (unsigned int)f2bf(lo) | ((unsigned int)f2bf(hi) << 16);
}
// raw HW exp2: safe here (|x| <= ~4, no denormal/overflow edge cases)
__device__ __forceinline__ float exp2_raw(float x) {
    float r;
    asm("v_exp_f32 %0, %1" : "=v"(r) : "v"(x));
    return r;
}

// ---------------- Kernel 1: conv3x3 + bias + BN partial stats + raw 2x2 maxpool ----------------
// Stats: plain-store per-block partials to pstat[blk][128] (no atomics, no pre-zero needed).
__global__ __launch_bounds__(256, 4) void k_conv(const float* __restrict__ x,
                                                 const float* __restrict__ cw,
                                                 const float* __restrict__ cb,
                                                 float* __restrict__ P,
                                                 float* __restrict__ pstat) {
    int blk = blockIdx.x;
    int cq = blk & 3, ph = (blk >> 2) & 63, b = blk >> 8;
    __shared__ float xl[3][4][36];
    int tid = threadIdx.x;
    for (int i = tid; i < 3 * 4 * 36; i += 256) {
        int ch = i / 144, rem = i % 144, row = rem / 36, col = rem % 36;
        int h = 2 * ph - 1 + row, gc = cq * 32 - 1 + col;
        float v = 0.f;
        if (h >= 0 && h < IMGD && gc >= 0 && gc < IMGD && col < 34)
            v = x[((b * 3 + ch) * IMGD + h) * IMGD + gc];
        xl[ch][row][col] = v;
    }
    __syncthreads();
    int c = tid >> 2, q = tid & 3;
    float w[27];
#pragma unroll
    for (int i = 0; i < 27; ++i) w[i] = cw[c * 27 + i];
    float bias = cb[c];
    float a0[8], a1[8];
#pragma unroll
    for (int j = 0; j < 8; ++j) { a0[j] = bias; a1[j] = bias; }
#pragma unroll
    for (int ch = 0; ch < 3; ++ch) {
        float rv[4][10];
#pragma unroll
        for (int rr = 0; rr < 4; ++rr)
#pragma unroll
            for (int t = 0; t < 10; ++t) rv[rr][t] = xl[ch][rr][q * 8 + t];
#pragma unroll
        for (int kh = 0; kh < 3; ++kh) {
            float w0 = w[ch * 9 + kh * 3], w1 = w[ch * 9 + kh * 3 + 1], w2 = w[ch * 9 + kh * 3 + 2];
#pragma unroll
            for (int j = 0; j < 8; ++j) {
                a0[j] += rv[kh][j] * w0 + rv[kh][j + 1] * w1 + rv[kh][j + 2] * w2;
                a1[j] += rv[kh + 1][j] * w0 + rv[kh + 1][j + 1] * w1 + rv[kh + 1][j + 2] * w2;
            }
        }
    }
    float s1 = 0.f, s2 = 0.f;
#pragma unroll
    for (int j = 0; j < 8; ++j) {
        s1 += a0[j] + a1[j];
        s2 += a0[j] * a0[j] + a1[j] * a1[j];
    }
    s1 += __shfl_xor(s1, 1); s1 += __shfl_xor(s1, 2);
    s2 += __shfl_xor(s2, 1); s2 += __shfl_xor(s2, 2);
    if (q == 0) {
        pstat[blk * 128 + c] = s1;
        pstat[blk * 128 + 64 + c] = s2;
    }
    float4 pv;
    float* pvf = (float*)&pv;
#pragma unroll
    for (int j4 = 0; j4 < 4; ++j4)
        pvf[j4] = fmaxf(fmaxf(a0[2 * j4], a0[2 * j4 + 1]), fmaxf(a1[2 * j4], a1[2 * j4 + 1]));
    *(float4*)(P + ((size_t)((b * 64 + c) * 64 + ph)) * 64 + cq * 16 + q * 4) = pv;
}

// ---------------- Kernel 1b: reduce pstat[512][128] -> stats[128], 128 blocks ----------------
__global__ __launch_bounds__(256) void k_stat(const float* __restrict__ pstat,
                                              float* __restrict__ stats) {
    __shared__ float red[256];
    int e = blockIdx.x;          // stat entry 0..127
    int tid = threadIdx.x;
    red[tid] = pstat[tid * 128 + e] + pstat[(tid + 256) * 128 + e];
    __syncthreads();
    for (int off = 128; off > 0; off >>= 1) {
        if (tid < off) red[tid] += red[tid + off];
        __syncthreads();
    }
    if (tid == 0) stats[e] = red[0];
}

// ---------------- Kernel 2: fused BN+ReLU + qkv MFMA GEMM, LDS-staged coalesced epilogue ----------------
// vT stored PAIR-PERMUTED: within each 32-key group, 8B-block b -> pos 2*(b&3)+(b>>2)
#define TW_S 72
__global__ __launch_bounds__(256) void k_bnqkv(const float* __restrict__ P,
                                               const float* __restrict__ stats,
                                               const float* __restrict__ gamma,
                                               const float* __restrict__ beta,
                                               const float* __restrict__ qw,
                                               const float* __restrict__ qb,
                                               float* __restrict__ q,
                                               unsigned short* __restrict__ kbf,
                                               unsigned short* __restrict__ vT) {
    __shared__ unsigned short sm2[(64 + 96) * TW_S];   // 11520 u16 = 23040 B
    unsigned short* lt = sm2;
    unsigned short* lw = sm2 + 64 * TW_S;
    int blk = blockIdx.x;
    int half = blk & 1, ph = (blk >> 1) & 63, b = blk >> 7;
    int tid = threadIdx.x;
    for (int idx = tid; idx < 96 * 16; idx += 256) {
        int nl = idx >> 4, c4 = (idx & 15) * 4;
        float4 wv = *(const float4*)(qw + (half * 96 + nl) * 64 + c4);
        *(uint2*)(lw + nl * TW_S + c4) = make_uint2(pk2(wv.x, wv.y), pk2(wv.z, wv.w));
    }
    const float invN = 1.f / (BB * IMGD * IMGD);
    for (int idx = tid; idx < 4096; idx += 256) {
        int c = idx >> 6, pw = idx & 63;
        float mu = stats[c] * invN;
        float var = stats[64 + c] * invN - mu * mu;
        float sc = rsqrtf(var + EPSV) * gamma[c];
        float sh = beta[c] - mu * sc;
        float mv = fmaxf(P[((size_t)((b * 64 + c) * 64 + ph)) * 64 + pw] * sc + sh, 0.f);
        lt[pw * TW_S + c] = f2bf(mv);
    }
    __syncthreads();
    int w = tid >> 6, l = tid & 63, m = l & 15, g = l >> 4;
    f32x4 acc[6];
#pragma unroll
    for (int nt = 0; nt < 6; ++nt) {
        float bb = qb[half * 96 + nt * 16 + m];
        acc[nt] = (f32x4){bb, bb, bb, bb};
    }
#pragma unroll
    for (int ks = 0; ks < 2; ++ks) {
        bf16x8 af = *(bf16x8*)(lt + (16 * w + m) * TW_S + ks * 32 + g * 8);
#pragma unroll
        for (int nt = 0; nt < 6; ++nt) {
            bf16x8 bf_ = *(bf16x8*)(lw + (nt * 16 + m) * TW_S + ks * 32 + g * 8);
            acc[nt] = __builtin_amdgcn_mfma_f32_16x16x32_bf16(af, bf_, acc[nt], 0, 0, 0);
        }
    }
    // ---- epilogue: stage everything in LDS, then coalesced vector stores ----
    __syncthreads();   // lt/lw dead
    if (half == 0) {
        float* lqf = (float*)sm2;
        unsigned short* kl = sm2 + 8448;
#pragma unroll
        for (int nt = 0; nt < 4; ++nt)
#pragma unroll
            for (int r = 0; r < 4; ++r)
                lqf[(16 * w + 4 * g + r) * 66 + nt * 16 + m] = acc[nt][r];
#pragma unroll
        for (int nt = 4; nt < 6; ++nt)
#pragma unroll
            for (int r = 0; r < 4; ++r)
                kl[((nt - 4) * 64 + 16 * w + 4 * g + r) * 16 + m] = f2bf(acc[nt][r]);
        __syncthreads();
#pragma unroll
        for (int h = 0; h < 4; ++h) {
            float* dst = q + ((size_t)((b * HEADS + h) * SS) + ph * 64) * 16;
            for (int i = tid; i < 1024; i += 256) {
                int s_l = i >> 2, d0 = (i & 3) * 4;
                *(float4*)(dst + s_l * 16 + d0) = *(float4*)(lqf + s_l * 66 + h * 16 + d0);
            }
        }
        {
            int h2 = tid >> 7, off = tid & 127;
            unsigned short* dst = kbf + ((size_t)(b * HEADS + h2) * SS + ph * 64) * 16;
            *(uint4*)(dst + off * 8) = *(uint4*)(kl + h2 * 1024 + off * 8);
        }
    } else {
        unsigned short* kl = sm2;
        unsigned short* vl = sm2 + 2048;
#pragma unroll
        for (int nt = 0; nt < 2; ++nt)
#pragma unroll
            for (int r = 0; r < 4; ++r)
                kl[(nt * 64 + 16 * w + 4 * g + r) * 16 + m] = f2bf(acc[nt][r]);
#pragma unroll
        for (int nt = 2; nt < 6; ++nt) {
            int hv = nt - 2;
#pragma unroll
            for (int r = 0; r < 4; ++r) {
                int s_l = 16 * w + 4 * g + r;
                int kk = s_l & 31, bbl = kk >> 2, e = kk & 3;
                int p = 2 * (bbl & 3) + (bbl >> 2);
                int s2l = (s_l & 32) | (p << 2) | e;
                vl[(hv * 16 + m) * 68 + s2l] = f2bf(acc[nt][r]);
            }
        }
        __syncthreads();
        {
            int h2 = tid >> 7, off = tid & 127;
            unsigned short* dst = kbf + ((size_t)(b * HEADS + 2 + h2) * SS + ph * 64) * 16;
            *(uint4*)(dst + off * 8) = *(uint4*)(kl + h2 * 1024 + off * 8);
        }
#pragma unroll
        for (int ii = 0; ii < 2; ++ii) {
            int i = tid + ii * 256;
            int hv = i >> 7, rem = i & 127, d = rem >> 3, c8 = rem & 7;
            unsigned short* dst = vT + ((size_t)((b * HEADS + hv) * 16 + d)) * SS + ph * 64 + c8 * 8;
            *(uint4*)dst = *(uint4*)(vl + (hv * 16 + d) * 68 + c8 * 8);
        }
    }
}

// ---------------- Kernel 3: rw bias table, bh-locked XCD placement ----------------
// rwt[bh][s][wk] = log2e * Q[s].Rw[(s&63)-wk+63]
__global__ __launch_bounds__(256) void k_rwt(const float* __restrict__ qbuf,
                                             const float* __restrict__ rpw,
                                             unsigned short* __restrict__ rwt) {
    __shared__ unsigned short tab[64 * 72];   // [q][wk], stride 72
    int blk = blockIdx.x;
    int bh = blk & 7, hq = blk >> 3;   // bh == xcd (blk%8 heuristic)
    int tid = threadIdx.x;
    int w = tid >> 6, l = tid & 63, m = l & 15, g = l >> 4;
    int wqh = w * 16 + m;
    const float L2E = 1.44269504f;
    bf16x8 qt = (bf16x8)(short)0;
    if (g < 2) {
        const float* qrow = qbuf + ((size_t)bh * SS + hq * 64 + wqh) * DIM + g * 8;
        float4 a = *(const float4*)qrow;
        float4 b2 = *(const float4*)(qrow + 4);
        unsigned int u[4] = {pk2(a.x, a.y), pk2(a.z, a.w), pk2(b2.x, b2.y), pk2(b2.z, b2.w)};
        qt = *(bf16x8*)u;
    }
#pragma unroll
    for (int t = 0; t < 8; ++t) {
        bf16x8 af = (bf16x8)(short)0;
        int idxr = t * 16 + m;
        if (g < 2 && idxr < 127) {
            const float4* rp = (const float4*)(rpw + idxr * 16 + g * 8);
            float4 a = rp[0], b2 = rp[1];
            unsigned int u[4] = {pk2(L2E * a.x, L2E * a.y), pk2(L2E * a.z, L2E * a.w),
                                 pk2(L2E * b2.x, L2E * b2.y), pk2(L2E * b2.z, L2E * b2.w)};
            af = *(bf16x8*)u;
        }
        f32x4 st = __builtin_amdgcn_mfma_f32_16x16x32_bf16(
            af, qt, (f32x4){0.f, 0.f, 0.f, 0.f}, 0, 0, 0);
#pragma unroll
        for (int r = 0; r < 4; ++r) {
            int idx = t * 16 + 4 * g + r;
            int wk = 63 + wqh - idx;
            if (wk >= 0 && wk < 64) tab[wqh * 72 + wk] = f2bf(st[r]);
        }
    }
    __syncthreads();
    unsigned short* dst = rwt + ((size_t)bh * SS + hq * 64) * 64;
#pragma unroll
    for (int i = tid; i < 512; i += 256) {
        int qr = i >> 3, c8 = i & 7;
        *(uint4*)(dst + qr * 64 + c8 * 8) = *(uint4*)(tab + qr * 72 + c8 * 8);
    }
}

// ---------------- Kernel 4: MFMA flash attention, pipelined K prefetch + setprio ----------------
// LDS u16 layout (10240 u16 = 20480 B), SHARED by both hq groups:
//   K  [256][24] @0      (48B stride)
//   V  [16][32x16B] @6144 (pair-permuted global layout, 16B-block XOR swizzle)
#define KK_O 0
#define V_O  6144

__global__ __launch_bounds__(512, 8) void k_attn(const float* __restrict__ qbuf,
                                                 const unsigned short* __restrict__ kbf,
                                                 const unsigned short* __restrict__ vT,
                                                 const float* __restrict__ rph,
                                                 const unsigned short* __restrict__ rwt,
                                                 float* __restrict__ oq,
                                                 float* __restrict__ lq) {
    __shared__ unsigned short sm[10240];
    int blk = blockIdx.x;
    // bh-locked XCD mapping: ALL blocks for one bh (all kc, all hp) on one XCD.
    int bh  = blk & 7;                 // == xcd under blk%8 round-robin
    int slot = blk >> 3;               // 0..127
    int kc  = slot >> 5;               // 0..3
    int hp  = slot & 31;
    int tid = threadIdx.x;
    int w = tid >> 6, l = tid & 63;
    int m = l & 15, g = l >> 4;
    int wq = (w & 3) * 16 + m;
    int hq = 2 * hp + (w >> 2);
    const float AC = 0.25f * 1.44269504f;

    // staging roles: waves 0-3 stage K, waves 4-7 stage V (16B x2 per thread)
    bool isK = tid < 256;
    int kt = tid & 255;
    int vd = kt & 15, g16 = kt >> 4;
    const uint4* base = isK
        ? (const uint4*)(kbf + ((size_t)bh * SS + kc * 1024 + kt) * 16)
        : (const uint4*)(vT + ((size_t)bh * 16 + vd) * SS + kc * 1024 + g16 * 16);
    int cstride = isK ? 512 : 16;   // in uint4 units
    uint4 r0 = base[0], r1 = base[1];
    int rmw = vd & 7, B0 = 2 * g16;
    int Ba = (B0 & 24) | ((B0 & 7) ^ rmw);
    int Bb = ((B0 + 1) & 24) | (((B0 + 1) & 7) ^ rmw);

    // Q fragment, AC-prescaled (lanes g<2)
    bf16x8 qtmp = (bf16x8)(short)0;
    if (g < 2) {
        const float* qrow = qbuf + ((size_t)bh * SS + hq * 64 + wq) * DIM + g * 8;
        float4 a = *(const float4*)qrow;
        float4 b2 = *(const float4*)(qrow + 4);
        unsigned int u[4] = {pk2(AC * a.x, AC * a.y), pk2(AC * a.z, AC * a.w),
                             pk2(AC * b2.x, AC * b2.y), pk2(AC * b2.z, AC * b2.w)};
        qtmp = *(bf16x8*)u;
    }

    // rh via one MFMA -> registers: lane (g,m) -> redistribute via shfl
    float rhq[4][4];
    {
        bf16x8 af = (bf16x8)(short)0;
        if (g < 2) {
            const float4* rp = (const float4*)(rph + (hq + 63 - (kc * 16 + m)) * 16 + g * 8);
            float4 a = rp[0], b2 = rp[1];
            unsigned int u[4] = {pk2(4.f * a.x, 4.f * a.y), pk2(4.f * a.z, 4.f * a.w),
                                 pk2(4.f * b2.x, 4.f * b2.y), pk2(4.f * b2.z, 4.f * b2.w)};
            af = *(bf16x8*)u;
        }
        f32x4 st = __builtin_amdgcn_mfma_f32_16x16x32_bf16(
            af, qtmp, (f32x4){0.f, 0.f, 0.f, 0.f}, 0, 0, 0);
        float stv[4], o16[4], o32[4], o48[4];
#pragma unroll
        for (int r = 0; r < 4; ++r) {
            stv[r] = st[r];
            o16[r] = __shfl_xor(st[r], 16);
            o32[r] = __shfl_xor(st[r], 32);
            o48[r] = __shfl_xor(st[r], 48);
        }
#pragma unroll
        for (int j = 0; j < 4; ++j) {
            int d = g ^ j;
#pragma unroll
            for (int r = 0; r < 4; ++r)
                rhq[j][r] = (d == 0) ? stv[r] : (d == 1) ? o16[r] : (d == 2) ? o32[r] : o48[r];
        }
    }

    // qv fragment variants: g<2 -> AC*Q; g>=2 -> rw rows from precomputed table
    bf16x8 qv0, qv1, qv2, qv3;
    if (g < 2) {
        qv0 = qv1 = qv2 = qv3 = qtmp;
    } else {
        const unsigned short* rb = rwt + ((size_t)bh * SS + hq * 64 + wq) * 64 + (g - 2) * 8;
        qv0 = *(const bf16x8*)(rb);
        qv1 = *(const bf16x8*)(rb + 16);
        qv2 = *(const bf16x8*)(rb + 32);
        qv3 = *(const bf16x8*)(rb + 48);
    }
    // delta A-frag for upper-K bias lanes: A[m][16+m] = 1
    unsigned int dw[4];
    int act = (g == 2) ? (m < 8 ? m : -1) : ((g == 3) ? (m >= 8 ? m - 8 : -1) : -1);
#pragma unroll
    for (int i2 = 0; i2 < 4; ++i2)
        dw[i2] = (act >= 0 && (act >> 1) == i2) ? (0x3F80u << (16 * (act & 1))) : 0u;
    bf16x8 dfrag = *(bf16x8*)dw;
    unsigned int ow_[4] = {0x3F803F80u, 0x3F803F80u, 0x3F803F80u, 0x3F803F80u};
    bf16x8 ones = *(bf16x8*)ow_;

    f32x4 oacc = {0.f, 0.f, 0.f, 0.f};
    f32x4 lacc = {0.f, 0.f, 0.f, 0.f};
    int rmr = m & 7;       // read-side row XOR

#pragma unroll
    for (int c = 0; c < 4; ++c) {
        __syncthreads();   // prev compute done reading LDS
        if (isK) {
            *(uint4*)(sm + KK_O + kt * 24) = r0;
            *(uint4*)(sm + KK_O + kt * 24 + 8) = r1;
        } else {
            *(uint4*)(sm + V_O + vd * 256 + Ba * 8) = r0;
            *(uint4*)(sm + V_O + vd * 256 + Bb * 8) = r1;
        }
        __syncthreads();
        if (c < 3) {   // issue next chunk's loads (hidden under compute)
            r0 = base[(c + 1) * cstride];
            r1 = base[(c + 1) * cstride + 1];
        }

        // prime the K-fragment pipeline for g2=0
        bf16x8 kf0 = dfrag, kf1 = dfrag;
        if (g < 2) {
            kf0 = *(bf16x8*)(sm + KK_O + (m) * 24 + g * 8);
            kf1 = *(bf16x8*)(sm + KK_O + (16 + m) * 24 + g * 8);
        }
#pragma unroll
        for (int g2 = 0; g2 < 8; ++g2) {
            float rhv = rhq[c][g2 >> 1];
            bf16x8 qsel0 = (g2 & 1) ? qv2 : qv0;
            bf16x8 qsel1 = (g2 & 1) ? qv3 : qv1;
            __builtin_amdgcn_s_setprio(1);
            f32x4 st0 = __builtin_amdgcn_mfma_f32_16x16x32_bf16(
                kf0, qsel0, (f32x4){0.f, 0.f, 0.f, 0.f}, 0, 0, 0);
            f32x4 st1 = __builtin_amdgcn_mfma_f32_16x16x32_bf16(
                kf1, qsel1, (f32x4){0.f, 0.f, 0.f, 0.f}, 0, 0, 0);
            __builtin_amdgcn_s_setprio(0);
            // early V read for this tile (independent of exp chain)
            int B = g2 * 4 + g;
            int Bs = (B & 24) | ((B & 7) ^ rmr);
            bf16x8 vf = *(bf16x8*)(sm + V_O + m * 256 + Bs * 8);
            // prefetch next tile's K fragments (latency hides under exp chain)
            if (g2 < 7 && g < 2) {
                kf0 = *(bf16x8*)(sm + KK_O + ((g2 + 1) * 32 + m) * 24 + g * 8);
                kf1 = *(bf16x8*)(sm + KK_O + ((g2 + 1) * 32 + 16 + m) * 24 + g * 8);
            }
            float p0 = exp2_raw(st0[0] + rhv);
            float p1 = exp2_raw(st0[1] + rhv);
            float p2 = exp2_raw(st0[2] + rhv);
            float p3 = exp2_raw(st0[3] + rhv);
            float p4 = exp2_raw(st1[0] + rhv);
            float p5 = exp2_raw(st1[1] + rhv);
            float p6 = exp2_raw(st1[2] + rhv);
            float p7 = exp2_raw(st1[3] + rhv);
            unsigned int pp[4];
            asm("v_cvt_pk_bf16_f32 %0, %1, %2" : "=v"(pp[0]) : "v"(p0), "v"(p1));
            asm("v_cvt_pk_bf16_f32 %0, %1, %2" : "=v"(pp[1]) : "v"(p2), "v"(p3));
            asm("v_cvt_pk_bf16_f32 %0, %1, %2" : "=v"(pp[2]) : "v"(p4), "v"(p5));
            asm("v_cvt_pk_bf16_f32 %0, %1, %2" : "=v"(pp[3]) : "v"(p6), "v"(p7));
            bf16x8 pfrag = *(bf16x8*)pp;
            __builtin_amdgcn_s_setprio(1);
            oacc = __builtin_amdgcn_mfma_f32_16x16x32_bf16(vf, pfrag, oacc, 0, 0, 0);
            lacc = __builtin_amdgcn_mfma_f32_16x16x32_bf16(ones, pfrag, lacc, 0, 0, 0);
            __builtin_amdgcn_s_setprio(0);
        }
    }

    // AoS coalesced partial store: one float4 per thread, wave covers dense 1KB
    int qg = bh * SS + hq * 64 + wq;
    if (g == 0) lq[kc * NQ + qg] = lacc[0];
    *(f32x4*)(oq + ((size_t)kc * NQ + qg) * 16 + 4 * g) = oacc;
}

// ---------------- Kernel 5: combine 4 key-split partials, normalize, query-mean ----------------
// No atomics: block partial -> red2[blk][16] plain store (accumulated by k_head).
__global__ __launch_bounds__(256) void k_red(const float* __restrict__ oq,
                                             const float* __restrict__ lq,
                                             float* __restrict__ red2) {
    __shared__ float wred[4][16];
    int qg = blockIdx.x * 256 + threadIdx.x;
    float lsum = lq[qg] + lq[NQ + qg] + lq[2 * NQ + qg] + lq[3 * NQ + qg];
    float inv = 1.f / lsum;
    f32x4 a0, a1, a2, a3;
    {
        const f32x4* p = (const f32x4*)(oq + (size_t)qg * 16);
        a0 = p[0]; a1 = p[1]; a2 = p[2]; a3 = p[3];
    }
#pragma unroll
    for (int kc = 1; kc < 4; ++kc) {
        const f32x4* p = (const f32x4*)(oq + ((size_t)kc * NQ + qg) * 16);
        a0 += p[0]; a1 += p[1]; a2 += p[2]; a3 += p[3];
    }
    float vals[16];
    *(f32x4*)(vals) = a0; *(f32x4*)(vals + 4) = a1;
    *(f32x4*)(vals + 8) = a2; *(f32x4*)(vals + 12) = a3;
#pragma unroll
    for (int d = 0; d < 16; ++d) {
        float val = vals[d] * inv;
        val += __shfl_down(val, 32);
        val += __shfl_down(val, 16);
        val += __shfl_down(val, 8);
        val += __shfl_down(val, 4);
        val += __shfl_down(val, 2);
        val += __shfl_down(val, 1);
        if ((threadIdx.x & 63) == 0) wred[threadIdx.x >> 6][d] = val;
    }
    __syncthreads();
    if (threadIdx.x < 16) {
        float s = wred[0][threadIdx.x] + wred[1][threadIdx.x] +
                  wred[2][threadIdx.x] + wred[3][threadIdx.x];
        red2[blockIdx.x * 16 + threadIdx.x] = s;
    }
}

// ---------------- Kernel 6: reduce red2 + mean + out_proj + fc ----------------
__global__ __launch_bounds__(128) void k_head(const float* __restrict__ red2,
                                              const float* __restrict__ ow,
                                              const float* __restrict__ ob,
                                              const float* __restrict__ fw,
                                              const float* __restrict__ fb,
                                              float* __restrict__ out) {
    __shared__ float accL[128];
    __shared__ float feat[2][64];
    int tid = threadIdx.x;
    {   // accL[bh*16+d] = sum over the 16 k_red blocks of that bh
        int bh = tid >> 4, d = tid & 15;
        float s = 0.f;
#pragma unroll
        for (int j = 0; j < 16; ++j) s += red2[bh * 256 + j * 16 + d];
        accL[tid] = s;
    }
    __syncthreads();
    int b = tid >> 6, c = tid & 63;
    float f2 = ob[c];
    const float invS = 1.f / (float)SS;
#pragma unroll
    for (int cc = 0; cc < 64; ++cc)
        f2 += (accL[b * 64 + cc] * invS) * ow[c * 64 + cc];
    feat[b][c] = f2;
    __syncthreads();
    if (tid < BB * NCLS) {
        int bb = tid >> 1, n = tid & 1;
        float r = fb[n];
#pragma unroll
        for (int cc = 0; cc < 64; ++cc) r += feat[bb][cc] * fw[n * 64 + cc];
        out[bb * NCLS + n] = r;
    }
}

extern "C" void kernel_launch(void* const* d_in, const int* in_sizes, int n_in,
                              void* d_out, int out_size, void* d_ws, size_t ws_size,
                              hipStream_t stream) {
    const float* x      = (const float*)d_in[0];
    const float* conv_w = (const float*)d_in[1];
    const float* conv_b = (const float*)d_in[2];
    const float* bn_g   = (const float*)d_in[3];
    const float* bn_b   = (const float*)d_in[4];
    const float* qkv_w  = (const float*)d_in[5];
    const float* qkv_b  = (const float*)d_in[6];
    const float* rph    = (const float*)d_in[7];
    const float* rpw    = (const float*)d_in[8];
    const float* out_w  = (const float*)d_in[9];
    const float* out_b  = (const float*)d_in[10];
    const float* fc_w   = (const float*)d_in[11];
    const float* fc_b   = (const float*)d_in[12];

    float* ws    = (float*)d_ws;
    float* oq    = ws + OQ_OFF;
    float* lq    = ws + LQ_OFF;
    float* P     = ws + P_OFF;
    unsigned short* kbf = (unsigned short*)(ws + KBF_OFF);
    unsigned short* vT  = (unsigned short*)(ws + VTB_OFF);
    float* stats = ws + STAT_OFF;
    float* q     = ws + Q_OFF;
    unsigned short* rwt = (unsigned short*)(ws + RWT_OFF);
    float* pstat = ws + RWT_OFF;    // overlay: dead before k_rwt writes rwt
    float* red2  = ws + KBF_OFF;    // overlay: kbf dead after k_attn

    // NO memset: all reductions are plain-store (fully written every launch)

    k_conv  <<<BB * PP * 4, 256, 0, stream>>>(x, conv_w, conv_b, P, pstat);
    k_stat  <<<128, 256, 0, stream>>>(pstat, stats);
    k_bnqkv <<<BB * PP * 2, 256, 0, stream>>>(P, stats, bn_g, bn_b, qkv_w, qkv_b, q, kbf, vT);
    k_rwt   <<<BB * HEADS * PP, 256, 0, stream>>>(q, rpw, rwt);
    k_attn  <<<BB * HEADS * 32 * 4, 512, 0, stream>>>(q, kbf, vT, rph, rwt, oq, lq);
    k_red   <<<NQ / 256, 256, 0, stream>>>(oq, lq, red2);
    k_head  <<<1, 128, 0, stream>>>(red2, out_w, out_b, fc_w, fc_b, (float*)d_out);
}

// Round 24
// 82.860 us; speedup vs baseline: 1.4635x; 1.4635x over previous
//
#include <hip/hip_runtime.h>
#include <math.h>

#define BB 2
#define CIN 3
#define IMGD 128
#define HID 64
#define HEADS 4
#define DIM 16
#define PP 64
#define SS 4096
#define NCLS 2
#define EPSV 1e-5f
#define NQ 32768

// ws layout in floats
#define OQ_OFF   0         // [4][NQ][16] = 2,097,152 (AoS, coalesced float4 stores)
#define P_OFF    0         // pooled conv pre-BN (overlays oq; dead before attn)
#define LQ_OFF   2097152   // [4][NQ] = 131,072
#define KBF_OFF  2228224   // bf16 K [8][4096][16]; red2[128][16] overlays after k_attn
#define VTB_OFF  2490368   // bf16 V^T [8][16][4096] (pair-permuted) -> 262,144 f32 slots
#define STAT_OFF 2752512   // 128
#define ACC_OFF  2752640   // 128 (unused now)
#define Q_OFF    2752768   // q f32 (b,h,s,d) 524,288
#define RWT_OFF  3277056   // bf16 rw table [8][4096][64]; pstat[512][128] overlays BEFORE k_rwt

typedef short bf16x8 __attribute__((ext_vector_type(8)));
typedef float f32x4 __attribute__((ext_vector_type(4)));

__device__ __forceinline__ unsigned short f2bf(float f) {
    unsigned int u = __float_as_uint(f);
    u += 0x7FFFu + ((u >> 16) & 1u);
    return (unsigned short)(u >> 16);
}
__device__ __forceinline__ unsigned int pk2(float lo, float hi) {
    return (unsigned int)f2bf(lo) | ((unsigned int)f2bf(hi) << 16);
}
// raw HW exp2: safe here (|x| <= ~4, no denormal/overflow edge cases)
__device__ __forceinline__ float exp2_raw(float x) {
    float r;
    asm("v_exp_f32 %0, %1" : "=v"(r) : "v"(x));
    return r;
}

// ---------------- Kernel 1: conv3x3 + bias + BN partial stats + raw 2x2 maxpool ----------------
// Stats: plain-store per-block partials to pstat[blk][128] (no atomics, no pre-zero needed).
__global__ __launch_bounds__(256, 4) void k_conv(const float* __restrict__ x,
                                                 const float* __restrict__ cw,
                                                 const float* __restrict__ cb,
                                                 float* __restrict__ P,
                                                 float* __restrict__ pstat) {
    int blk = blockIdx.x;
    int cq = blk & 3, ph = (blk >> 2) & 63, b = blk >> 8;
    __shared__ float xl[3][4][36];
    int tid = threadIdx.x;
    for (int i = tid; i < 3 * 4 * 36; i += 256) {
        int ch = i / 144, rem = i % 144, row = rem / 36, col = rem % 36;
        int h = 2 * ph - 1 + row, gc = cq * 32 - 1 + col;
        float v = 0.f;
        if (h >= 0 && h < IMGD && gc >= 0 && gc < IMGD && col < 34)
            v = x[((b * 3 + ch) * IMGD + h) * IMGD + gc];
        xl[ch][row][col] = v;
    }
    __syncthreads();
    int c = tid >> 2, q = tid & 3;
    float w[27];
#pragma unroll
    for (int i = 0; i < 27; ++i) w[i] = cw[c * 27 + i];
    float bias = cb[c];
    float a0[8], a1[8];
#pragma unroll
    for (int j = 0; j < 8; ++j) { a0[j] = bias; a1[j] = bias; }
#pragma unroll
    for (int ch = 0; ch < 3; ++ch) {
        float rv[4][10];
#pragma unroll
        for (int rr = 0; rr < 4; ++rr)
#pragma unroll
            for (int t = 0; t < 10; ++t) rv[rr][t] = xl[ch][rr][q * 8 + t];
#pragma unroll
        for (int kh = 0; kh < 3; ++kh) {
            float w0 = w[ch * 9 + kh * 3], w1 = w[ch * 9 + kh * 3 + 1], w2 = w[ch * 9 + kh * 3 + 2];
#pragma unroll
            for (int j = 0; j < 8; ++j) {
                a0[j] += rv[kh][j] * w0 + rv[kh][j + 1] * w1 + rv[kh][j + 2] * w2;
                a1[j] += rv[kh + 1][j] * w0 + rv[kh + 1][j + 1] * w1 + rv[kh + 1][j + 2] * w2;
            }
        }
    }
    float s1 = 0.f, s2 = 0.f;
#pragma unroll
    for (int j = 0; j < 8; ++j) {
        s1 += a0[j] + a1[j];
        s2 += a0[j] * a0[j] + a1[j] * a1[j];
    }
    s1 += __shfl_xor(s1, 1); s1 += __shfl_xor(s1, 2);
    s2 += __shfl_xor(s2, 1); s2 += __shfl_xor(s2, 2);
    if (q == 0) {
        pstat[blk * 128 + c] = s1;
        pstat[blk * 128 + 64 + c] = s2;
    }
    float4 pv;
    float* pvf = (float*)&pv;
#pragma unroll
    for (int j4 = 0; j4 < 4; ++j4)
        pvf[j4] = fmaxf(fmaxf(a0[2 * j4], a0[2 * j4 + 1]), fmaxf(a1[2 * j4], a1[2 * j4 + 1]));
    *(float4*)(P + ((size_t)((b * 64 + c) * 64 + ph)) * 64 + cq * 16 + q * 4) = pv;
}

// ---------------- Kernel 1b: reduce pstat[512][128] -> stats[128], 128 blocks ----------------
__global__ __launch_bounds__(256) void k_stat(const float* __restrict__ pstat,
                                              float* __restrict__ stats) {
    __shared__ float red[256];
    int e = blockIdx.x;          // stat entry 0..127
    int tid = threadIdx.x;
    red[tid] = pstat[tid * 128 + e] + pstat[(tid + 256) * 128 + e];
    __syncthreads();
    for (int off = 128; off > 0; off >>= 1) {
        if (tid < off) red[tid] += red[tid + off];
        __syncthreads();
    }
    if (tid == 0) stats[e] = red[0];
}

// ---------------- Kernel 2: fused BN+ReLU + qkv MFMA GEMM, LDS-staged coalesced epilogue ----------------
// vT stored PAIR-PERMUTED: within each 32-key group, 8B-block b -> pos 2*(b&3)+(b>>2)
#define TW_S 72
__global__ __launch_bounds__(256) void k_bnqkv(const float* __restrict__ P,
                                               const float* __restrict__ stats,
                                               const float* __restrict__ gamma,
                                               const float* __restrict__ beta,
                                               const float* __restrict__ qw,
                                               const float* __restrict__ qb,
                                               float* __restrict__ q,
                                               unsigned short* __restrict__ kbf,
                                               unsigned short* __restrict__ vT) {
    __shared__ unsigned short sm2[(64 + 96) * TW_S];   // 11520 u16 = 23040 B
    unsigned short* lt = sm2;
    unsigned short* lw = sm2 + 64 * TW_S;
    int blk = blockIdx.x;
    int half = blk & 1, ph = (blk >> 1) & 63, b = blk >> 7;
    int tid = threadIdx.x;
    for (int idx = tid; idx < 96 * 16; idx += 256) {
        int nl = idx >> 4, c4 = (idx & 15) * 4;
        float4 wv = *(const float4*)(qw + (half * 96 + nl) * 64 + c4);
        *(uint2*)(lw + nl * TW_S + c4) = make_uint2(pk2(wv.x, wv.y), pk2(wv.z, wv.w));
    }
    const float invN = 1.f / (BB * IMGD * IMGD);
    for (int idx = tid; idx < 4096; idx += 256) {
        int c = idx >> 6, pw = idx & 63;
        float mu = stats[c] * invN;
        float var = stats[64 + c] * invN - mu * mu;
        float sc = rsqrtf(var + EPSV) * gamma[c];
        float sh = beta[c] - mu * sc;
        float mv = fmaxf(P[((size_t)((b * 64 + c) * 64 + ph)) * 64 + pw] * sc + sh, 0.f);
        lt[pw * TW_S + c] = f2bf(mv);
    }
    __syncthreads();
    int w = tid >> 6, l = tid & 63, m = l & 15, g = l >> 4;
    f32x4 acc[6];
#pragma unroll
    for (int nt = 0; nt < 6; ++nt) {
        float bb = qb[half * 96 + nt * 16 + m];
        acc[nt] = (f32x4){bb, bb, bb, bb};
    }
#pragma unroll
    for (int ks = 0; ks < 2; ++ks) {
        bf16x8 af = *(bf16x8*)(lt + (16 * w + m) * TW_S + ks * 32 + g * 8);
#pragma unroll
        for (int nt = 0; nt < 6; ++nt) {
            bf16x8 bf_ = *(bf16x8*)(lw + (nt * 16 + m) * TW_S + ks * 32 + g * 8);
            acc[nt] = __builtin_amdgcn_mfma_f32_16x16x32_bf16(af, bf_, acc[nt], 0, 0, 0);
        }
    }
    // ---- epilogue: stage everything in LDS, then coalesced vector stores ----
    __syncthreads();   // lt/lw dead
    if (half == 0) {
        float* lqf = (float*)sm2;
        unsigned short* kl = sm2 + 8448;
#pragma unroll
        for (int nt = 0; nt < 4; ++nt)
#pragma unroll
            for (int r = 0; r < 4; ++r)
                lqf[(16 * w + 4 * g + r) * 66 + nt * 16 + m] = acc[nt][r];
#pragma unroll
        for (int nt = 4; nt < 6; ++nt)
#pragma unroll
            for (int r = 0; r < 4; ++r)
                kl[((nt - 4) * 64 + 16 * w + 4 * g + r) * 16 + m] = f2bf(acc[nt][r]);
        __syncthreads();
#pragma unroll
        for (int h = 0; h < 4; ++h) {
            float* dst = q + ((size_t)((b * HEADS + h) * SS) + ph * 64) * 16;
            for (int i = tid; i < 1024; i += 256) {
                int s_l = i >> 2, d0 = (i & 3) * 4;
                *(float4*)(dst + s_l * 16 + d0) = *(float4*)(lqf + s_l * 66 + h * 16 + d0);
            }
        }
        {
            int h2 = tid >> 7, off = tid & 127;
            unsigned short* dst = kbf + ((size_t)(b * HEADS + h2) * SS + ph * 64) * 16;
            *(uint4*)(dst + off * 8) = *(uint4*)(kl + h2 * 1024 + off * 8);
        }
    } else {
        unsigned short* kl = sm2;
        unsigned short* vl = sm2 + 2048;
#pragma unroll
        for (int nt = 0; nt < 2; ++nt)
#pragma unroll
            for (int r = 0; r < 4; ++r)
                kl[(nt * 64 + 16 * w + 4 * g + r) * 16 + m] = f2bf(acc[nt][r]);
#pragma unroll
        for (int nt = 2; nt < 6; ++nt) {
            int hv = nt - 2;
#pragma unroll
            for (int r = 0; r < 4; ++r) {
                int s_l = 16 * w + 4 * g + r;
                int kk = s_l & 31, bbl = kk >> 2, e = kk & 3;
                int p = 2 * (bbl & 3) + (bbl >> 2);
                int s2l = (s_l & 32) | (p << 2) | e;
                vl[(hv * 16 + m) * 68 + s2l] = f2bf(acc[nt][r]);
            }
        }
        __syncthreads();
        {
            int h2 = tid >> 7, off = tid & 127;
            unsigned short* dst = kbf + ((size_t)(b * HEADS + 2 + h2) * SS + ph * 64) * 16;
            *(uint4*)(dst + off * 8) = *(uint4*)(kl + h2 * 1024 + off * 8);
        }
#pragma unroll
        for (int ii = 0; ii < 2; ++ii) {
            int i = tid + ii * 256;
            int hv = i >> 7, rem = i & 127, d = rem >> 3, c8 = rem & 7;
            unsigned short* dst = vT + ((size_t)((b * HEADS + hv) * 16 + d)) * SS + ph * 64 + c8 * 8;
            *(uint4*)dst = *(uint4*)(vl + (hv * 16 + d) * 68 + c8 * 8);
        }
    }
}

// ---------------- Kernel 3: rw bias table, bh-locked XCD placement ----------------
// rwt[bh][s][wk] = log2e * Q[s].Rw[(s&63)-wk+63]
__global__ __launch_bounds__(256) void k_rwt(const float* __restrict__ qbuf,
                                             const float* __restrict__ rpw,
                                             unsigned short* __restrict__ rwt) {
    __shared__ unsigned short tab[64 * 72];   // [q][wk], stride 72
    int blk = blockIdx.x;
    int bh = blk & 7, hq = blk >> 3;   // bh == xcd (blk%8 heuristic)
    int tid = threadIdx.x;
    int w = tid >> 6, l = tid & 63, m = l & 15, g = l >> 4;
    int wqh = w * 16 + m;
    const float L2E = 1.44269504f;
    bf16x8 qt = (bf16x8)(short)0;
    if (g < 2) {
        const float* qrow = qbuf + ((size_t)bh * SS + hq * 64 + wqh) * DIM + g * 8;
        float4 a = *(const float4*)qrow;
        float4 b2 = *(const float4*)(qrow + 4);
        unsigned int u[4] = {pk2(a.x, a.y), pk2(a.z, a.w), pk2(b2.x, b2.y), pk2(b2.z, b2.w)};
        qt = *(bf16x8*)u;
    }
#pragma unroll
    for (int t = 0; t < 8; ++t) {
        bf16x8 af = (bf16x8)(short)0;
        int idxr = t * 16 + m;
        if (g < 2 && idxr < 127) {
            const float4* rp = (const float4*)(rpw + idxr * 16 + g * 8);
            float4 a = rp[0], b2 = rp[1];
            unsigned int u[4] = {pk2(L2E * a.x, L2E * a.y), pk2(L2E * a.z, L2E * a.w),
                                 pk2(L2E * b2.x, L2E * b2.y), pk2(L2E * b2.z, L2E * b2.w)};
            af = *(bf16x8*)u;
        }
        f32x4 st = __builtin_amdgcn_mfma_f32_16x16x32_bf16(
            af, qt, (f32x4){0.f, 0.f, 0.f, 0.f}, 0, 0, 0);
#pragma unroll
        for (int r = 0; r < 4; ++r) {
            int idx = t * 16 + 4 * g + r;
            int wk = 63 + wqh - idx;
            if (wk >= 0 && wk < 64) tab[wqh * 72 + wk] = f2bf(st[r]);
        }
    }
    __syncthreads();
    unsigned short* dst = rwt + ((size_t)bh * SS + hq * 64) * 64;
#pragma unroll
    for (int i = tid; i < 512; i += 256) {
        int qr = i >> 3, c8 = i & 7;
        *(uint4*)(dst + qr * 64 + c8 * 8) = *(uint4*)(tab + qr * 72 + c8 * 8);
    }
}

// ---------------- Kernel 4: MFMA flash attention, bh-locked XCD, AoS oq stores ----------------
// LDS u16 layout (10240 u16 = 20480 B), SHARED by both hq groups:
//   K  [256][24] @0      (48B stride)
//   V  [16][32x16B] @6144 (pair-permuted global layout, 16B-block XOR swizzle)
#define KK_O 0
#define V_O  6144

__global__ __launch_bounds__(512, 8) void k_attn(const float* __restrict__ qbuf,
                                                 const unsigned short* __restrict__ kbf,
                                                 const unsigned short* __restrict__ vT,
                                                 const float* __restrict__ rph,
                                                 const unsigned short* __restrict__ rwt,
                                                 float* __restrict__ oq,
                                                 float* __restrict__ lq) {
    __shared__ unsigned short sm[10240];
    int blk = blockIdx.x;
    // bh-locked XCD mapping: ALL blocks for one bh (all kc, all hp) on one XCD.
    int bh  = blk & 7;                 // == xcd under blk%8 round-robin
    int slot = blk >> 3;               // 0..127
    int kc  = slot >> 5;               // 0..3
    int hp  = slot & 31;
    int tid = threadIdx.x;
    int w = tid >> 6, l = tid & 63;
    int m = l & 15, g = l >> 4;
    int wq = (w & 3) * 16 + m;
    int hq = 2 * hp + (w >> 2);
    const float AC = 0.25f * 1.44269504f;

    // staging roles: waves 0-3 stage K, waves 4-7 stage V (16B x2 per thread)
    bool isK = tid < 256;
    int kt = tid & 255;
    int vd = kt & 15, g16 = kt >> 4;
    const uint4* base = isK
        ? (const uint4*)(kbf + ((size_t)bh * SS + kc * 1024 + kt) * 16)
        : (const uint4*)(vT + ((size_t)bh * 16 + vd) * SS + kc * 1024 + g16 * 16);
    int cstride = isK ? 512 : 16;   // in uint4 units
    uint4 r0 = base[0], r1 = base[1];
    int rmw = vd & 7, B0 = 2 * g16;
    int Ba = (B0 & 24) | ((B0 & 7) ^ rmw);
    int Bb = ((B0 + 1) & 24) | (((B0 + 1) & 7) ^ rmw);

    // Q fragment, AC-prescaled (lanes g<2)
    bf16x8 qtmp = (bf16x8)(short)0;
    if (g < 2) {
        const float* qrow = qbuf + ((size_t)bh * SS + hq * 64 + wq) * DIM + g * 8;
        float4 a = *(const float4*)qrow;
        float4 b2 = *(const float4*)(qrow + 4);
        unsigned int u[4] = {pk2(AC * a.x, AC * a.y), pk2(AC * a.z, AC * a.w),
                             pk2(AC * b2.x, AC * b2.y), pk2(AC * b2.z, AC * b2.w)};
        qtmp = *(bf16x8*)u;
    }

    // rh via one MFMA -> registers: lane (g,m) -> redistribute via shfl
    float rhq[4][4];
    {
        bf16x8 af = (bf16x8)(short)0;
        if (g < 2) {
            const float4* rp = (const float4*)(rph + (hq + 63 - (kc * 16 + m)) * 16 + g * 8);
            float4 a = rp[0], b2 = rp[1];
            unsigned int u[4] = {pk2(4.f * a.x, 4.f * a.y), pk2(4.f * a.z, 4.f * a.w),
                                 pk2(4.f * b2.x, 4.f * b2.y), pk2(4.f * b2.z, 4.f * b2.w)};
            af = *(bf16x8*)u;
        }
        f32x4 st = __builtin_amdgcn_mfma_f32_16x16x32_bf16(
            af, qtmp, (f32x4){0.f, 0.f, 0.f, 0.f}, 0, 0, 0);
        float stv[4], o16[4], o32[4], o48[4];
#pragma unroll
        for (int r = 0; r < 4; ++r) {
            stv[r] = st[r];
            o16[r] = __shfl_xor(st[r], 16);
            o32[r] = __shfl_xor(st[r], 32);
            o48[r] = __shfl_xor(st[r], 48);
        }
#pragma unroll
        for (int j = 0; j < 4; ++j) {
            int d = g ^ j;
#pragma unroll
            for (int r = 0; r < 4; ++r)
                rhq[j][r] = (d == 0) ? stv[r] : (d == 1) ? o16[r] : (d == 2) ? o32[r] : o48[r];
        }
    }

    // qv fragment variants: g<2 -> AC*Q; g>=2 -> rw rows from precomputed table
    bf16x8 qv0, qv1, qv2, qv3;
    if (g < 2) {
        qv0 = qv1 = qv2 = qv3 = qtmp;
    } else {
        const unsigned short* rb = rwt + ((size_t)bh * SS + hq * 64 + wq) * 64 + (g - 2) * 8;
        qv0 = *(const bf16x8*)(rb);
        qv1 = *(const bf16x8*)(rb + 16);
        qv2 = *(const bf16x8*)(rb + 32);
        qv3 = *(const bf16x8*)(rb + 48);
    }
    // delta A-frag for upper-K bias lanes: A[m][16+m] = 1
    unsigned int dw[4];
    int act = (g == 2) ? (m < 8 ? m : -1) : ((g == 3) ? (m >= 8 ? m - 8 : -1) : -1);
#pragma unroll
    for (int i2 = 0; i2 < 4; ++i2)
        dw[i2] = (act >= 0 && (act >> 1) == i2) ? (0x3F80u << (16 * (act & 1))) : 0u;
    bf16x8 dfrag = *(bf16x8*)dw;
    unsigned int ow_[4] = {0x3F803F80u, 0x3F803F80u, 0x3F803F80u, 0x3F803F80u};
    bf16x8 ones = *(bf16x8*)ow_;

    f32x4 oacc = {0.f, 0.f, 0.f, 0.f};
    f32x4 lacc = {0.f, 0.f, 0.f, 0.f};
    int rmr = m & 7;       // read-side row XOR

#pragma unroll
    for (int c = 0; c < 4; ++c) {
        __syncthreads();   // prev compute done reading LDS
        if (isK) {
            *(uint4*)(sm + KK_O + kt * 24) = r0;
            *(uint4*)(sm + KK_O + kt * 24 + 8) = r1;
        } else {
            *(uint4*)(sm + V_O + vd * 256 + Ba * 8) = r0;
            *(uint4*)(sm + V_O + vd * 256 + Bb * 8) = r1;
        }
        __syncthreads();
        if (c < 3) {   // issue next chunk's loads (hidden under compute)
            r0 = base[(c + 1) * cstride];
            r1 = base[(c + 1) * cstride + 1];
        }

#pragma unroll
        for (int g2 = 0; g2 < 8; ++g2) {
            const int kk0 = g2 * 32;
            float rhv = rhq[c][g2 >> 1];
            // issue BOTH independent QK MFMAs first, then exps, then pack+PV
            bf16x8 kf0 = dfrag, kf1 = dfrag;
            if (g < 2) {
                kf0 = *(bf16x8*)(sm + KK_O + (kk0 + m) * 24 + g * 8);
                kf1 = *(bf16x8*)(sm + KK_O + (kk0 + 16 + m) * 24 + g * 8);
            }
            bf16x8 qsel0 = (g2 & 1) ? qv2 : qv0;
            bf16x8 qsel1 = (g2 & 1) ? qv3 : qv1;
            f32x4 st0 = __builtin_amdgcn_mfma_f32_16x16x32_bf16(
                kf0, qsel0, (f32x4){0.f, 0.f, 0.f, 0.f}, 0, 0, 0);
            f32x4 st1 = __builtin_amdgcn_mfma_f32_16x16x32_bf16(
                kf1, qsel1, (f32x4){0.f, 0.f, 0.f, 0.f}, 0, 0, 0);
            float p0 = exp2_raw(st0[0] + rhv);
            float p1 = exp2_raw(st0[1] + rhv);
            float p2 = exp2_raw(st0[2] + rhv);
            float p3 = exp2_raw(st0[3] + rhv);
            float p4 = exp2_raw(st1[0] + rhv);
            float p5 = exp2_raw(st1[1] + rhv);
            float p6 = exp2_raw(st1[2] + rhv);
            float p7 = exp2_raw(st1[3] + rhv);
            unsigned int pp[4];
            asm("v_cvt_pk_bf16_f32 %0, %1, %2" : "=v"(pp[0]) : "v"(p0), "v"(p1));
            asm("v_cvt_pk_bf16_f32 %0, %1, %2" : "=v"(pp[1]) : "v"(p2), "v"(p3));
            asm("v_cvt_pk_bf16_f32 %0, %1, %2" : "=v"(pp[2]) : "v"(p4), "v"(p5));
            asm("v_cvt_pk_bf16_f32 %0, %1, %2" : "=v"(pp[3]) : "v"(p6), "v"(p7));
            bf16x8 pfrag = *(bf16x8*)pp;
            int B = g2 * 4 + g;
            int Bs = (B & 24) | ((B & 7) ^ rmr);
            bf16x8 vf = *(bf16x8*)(sm + V_O + m * 256 + Bs * 8);
            oacc = __builtin_amdgcn_mfma_f32_16x16x32_bf16(vf, pfrag, oacc, 0, 0, 0);
            lacc = __builtin_amdgcn_mfma_f32_16x16x32_bf16(ones, pfrag, lacc, 0, 0, 0);
        }
    }

    // AoS coalesced partial store: one float4 per thread, wave covers dense 1KB
    int qg = bh * SS + hq * 64 + wq;
    if (g == 0) lq[kc * NQ + qg] = lacc[0];
    *(f32x4*)(oq + ((size_t)kc * NQ + qg) * 16 + 4 * g) = oacc;
}

// ---------------- Kernel 5: combine 4 key-split partials, normalize, query-mean ----------------
// No atomics: block partial -> red2[blk][16] plain store (accumulated by k_head).
__global__ __launch_bounds__(256) void k_red(const float* __restrict__ oq,
                                             const float* __restrict__ lq,
                                             float* __restrict__ red2) {
    __shared__ float wred[4][16];
    int qg = blockIdx.x * 256 + threadIdx.x;
    float lsum = lq[qg] + lq[NQ + qg] + lq[2 * NQ + qg] + lq[3 * NQ + qg];
    float inv = 1.f / lsum;
    f32x4 a0, a1, a2, a3;
    {
        const f32x4* p = (const f32x4*)(oq + (size_t)qg * 16);
        a0 = p[0]; a1 = p[1]; a2 = p[2]; a3 = p[3];
    }
#pragma unroll
    for (int kc = 1; kc < 4; ++kc) {
        const f32x4* p = (const f32x4*)(oq + ((size_t)kc * NQ + qg) * 16);
        a0 += p[0]; a1 += p[1]; a2 += p[2]; a3 += p[3];
    }
    float vals[16];
    *(f32x4*)(vals) = a0; *(f32x4*)(vals + 4) = a1;
    *(f32x4*)(vals + 8) = a2; *(f32x4*)(vals + 12) = a3;
#pragma unroll
    for (int d = 0; d < 16; ++d) {
        float val = vals[d] * inv;
        val += __shfl_down(val, 32);
        val += __shfl_down(val, 16);
        val += __shfl_down(val, 8);
        val += __shfl_down(val, 4);
        val += __shfl_down(val, 2);
        val += __shfl_down(val, 1);
        if ((threadIdx.x & 63) == 0) wred[threadIdx.x >> 6][d] = val;
    }
    __syncthreads();
    if (threadIdx.x < 16) {
        float s = wred[0][threadIdx.x] + wred[1][threadIdx.x] +
                  wred[2][threadIdx.x] + wred[3][threadIdx.x];
        red2[blockIdx.x * 16 + threadIdx.x] = s;
    }
}

// ---------------- Kernel 6: reduce red2 + mean + out_proj + fc ----------------
__global__ __launch_bounds__(128) void k_head(const float* __restrict__ red2,
                                              const float* __restrict__ ow,
                                              const float* __restrict__ ob,
                                              const float* __restrict__ fw,
                                              const float* __restrict__ fb,
                                              float* __restrict__ out) {
    __shared__ float accL[128];
    __shared__ float feat[2][64];
    int tid = threadIdx.x;
    {   // accL[bh*16+d] = sum over the 16 k_red blocks of that bh
        int bh = tid >> 4, d = tid & 15;
        float s = 0.f;
#pragma unroll
        for (int j = 0; j < 16; ++j) s += red2[bh * 256 + j * 16 + d];
        accL[tid] = s;
    }
    __syncthreads();
    int b = tid >> 6, c = tid & 63;
    float f2 = ob[c];
    const float invS = 1.f / (float)SS;
#pragma unroll
    for (int cc = 0; cc < 64; ++cc)
        f2 += (accL[b * 64 + cc] * invS) * ow[c * 64 + cc];
    feat[b][c] = f2;
    __syncthreads();
    if (tid < BB * NCLS) {
        int bb = tid >> 1, n = tid & 1;
        float r = fb[n];
#pragma unroll
        for (int cc = 0; cc < 64; ++cc) r += feat[bb][cc] * fw[n * 64 + cc];
        out[bb * NCLS + n] = r;
    }
}

extern "C" void kernel_launch(void* const* d_in, const int* in_sizes, int n_in,
                              void* d_out, int out_size, void* d_ws, size_t ws_size,
                              hipStream_t stream) {
    const float* x      = (const float*)d_in[0];
    const float* conv_w = (const float*)d_in[1];
    const float* conv_b = (const float*)d_in[2];
    const float* bn_g   = (const float*)d_in[3];
    const float* bn_b   = (const float*)d_in[4];
    const float* qkv_w  = (const float*)d_in[5];
    const float* qkv_b  = (const float*)d_in[6];
    const float* rph    = (const float*)d_in[7];
    const float* rpw    = (const float*)d_in[8];
    const float* out_w  = (const float*)d_in[9];
    const float* out_b  = (const float*)d_in[10];
    const float* fc_w   = (const float*)d_in[11];
    const float* fc_b   = (const float*)d_in[12];

    float* ws    = (float*)d_ws;
    float* oq    = ws + OQ_OFF;
    float* lq    = ws + LQ_OFF;
    float* P     = ws + P_OFF;
    unsigned short* kbf = (unsigned short*)(ws + KBF_OFF);
    unsigned short* vT  = (unsigned short*)(ws + VTB_OFF);
    float* stats = ws + STAT_OFF;
    float* q     = ws + Q_OFF;
    unsigned short* rwt = (unsigned short*)(ws + RWT_OFF);
    float* pstat = ws + RWT_OFF;    // overlay: dead before k_rwt writes rwt
    float* red2  = ws + KBF_OFF;    // overlay: kbf dead after k_attn

    // NO memset: all reductions are plain-store (fully written every launch)

    k_conv  <<<BB * PP * 4, 256, 0, stream>>>(x, conv_w, conv_b, P, pstat);
    k_stat  <<<128, 256, 0, stream>>>(pstat, stats);
    k_bnqkv <<<BB * PP * 2, 256, 0, stream>>>(P, stats, bn_g, bn_b, qkv_w, qkv_b, q, kbf, vT);
    k_rwt   <<<BB * HEADS * PP, 256, 0, stream>>>(q, rpw, rwt);
    k_attn  <<<BB * HEADS * 32 * 4, 512, 0, stream>>>(q, kbf, vT, rph, rwt, oq, lq);
    k_red   <<<NQ / 256, 256, 0, stream>>>(oq, lq, red2);
    k_head  <<<1, 128, 0, stream>>>(red2, out_w, out_b, fc_w, fc_b, (float*)d_out);
}